// Round 4
// baseline (108.803 us; speedup 1.0000x reference)
//
#include <hip/hip_runtime.h>

// Problem constants (fixed by the reference file)
#define NN 8192
#define DIN 256
#define DD 256
static const long long PP = (long long)NN * (NN - 1) / 2;   // 33,550,336

// ---------------------------------------------------------------------------
// Kernel 1: per-node projections, with the weight-combine fused in.
// Each block redundantly computes in LDS:
//   M[i][0..1] = sum_j W_enc[i][j] * W_cls[j][0..1]        (A projection)
//   M[i][2..3] = sum_j W_enc[i][j] * W_cls[256+j][0..1]    (B projection)
//   off[0..1]  = b_enc . W_cls[:256][:,c] + b_cls[c]
//   off[2..3]  = b_enc . W_cls[256:][:,c]
// then AB[n] = { A0, A1, B0, B1 } = nodes[n] @ M + off  for its node slice.
// ---------------------------------------------------------------------------
__global__ __launch_bounds__(256) void ab_kernel(
    const float* __restrict__ nodes,   // [8192][256]
    const float* __restrict__ W_enc,   // [256][256]
    const float* __restrict__ b_enc,   // [256]
    const float* __restrict__ W_cls,   // [512][2]
    const float* __restrict__ b_cls,   // [2]
    float4* __restrict__ AB)           // [8192] out
{
    __shared__ float wc[1024];         // W_cls staged: [512][2]
    __shared__ float Ms[1024];         // M [256][4]
    __shared__ float offs[4];
    const int tid = threadIdx.x;
    for (int i = tid; i < 1024; i += 256) wc[i] = W_cls[i];
    __syncthreads();

    // --- M row `tid` ---
    {
        float a0 = 0.f, a1 = 0.f, a2 = 0.f, a3 = 0.f;
        const float4* wrow = (const float4*)(W_enc + (long long)tid * DIN);
        #pragma unroll 8
        for (int i = 0; i < DIN / 4; ++i) {
            const float4 v = wrow[i];
            const int j = i * 4;
            a0 += v.x * wc[(j+0)*2+0] + v.y * wc[(j+1)*2+0]
                + v.z * wc[(j+2)*2+0] + v.w * wc[(j+3)*2+0];
            a1 += v.x * wc[(j+0)*2+1] + v.y * wc[(j+1)*2+1]
                + v.z * wc[(j+2)*2+1] + v.w * wc[(j+3)*2+1];
            a2 += v.x * wc[(DD+j+0)*2+0] + v.y * wc[(DD+j+1)*2+0]
                + v.z * wc[(DD+j+2)*2+0] + v.w * wc[(DD+j+3)*2+0];
            a3 += v.x * wc[(DD+j+0)*2+1] + v.y * wc[(DD+j+1)*2+1]
                + v.z * wc[(DD+j+2)*2+1] + v.w * wc[(DD+j+3)*2+1];
        }
        Ms[tid*4+0] = a0; Ms[tid*4+1] = a1; Ms[tid*4+2] = a2; Ms[tid*4+3] = a3;
    }

    // --- off (threads 0..3) ---
    if (tid < 4) {
        const int c = tid & 1;
        const int base = (tid < 2) ? 0 : DD;
        float o0 = 0.f, o1 = 0.f, o2 = 0.f, o3 = 0.f;
        for (int j = 0; j < DIN; j += 4) {
            o0 += b_enc[j+0] * wc[(base+j+0)*2+c];
            o1 += b_enc[j+1] * wc[(base+j+1)*2+c];
            o2 += b_enc[j+2] * wc[(base+j+2)*2+c];
            o3 += b_enc[j+3] * wc[(base+j+3)*2+c];
        }
        float o = (o0 + o1) + (o2 + o3);
        if (tid < 2) o += b_cls[tid];     // fold b_cls into the A half
        offs[tid] = o;
    }
    __syncthreads();

    // --- per-node projections ---
    for (int n = blockIdx.x * 256 + tid; n < NN; n += gridDim.x * 256) {
        float a0 = offs[0], a1 = offs[1], a2 = offs[2], a3 = offs[3];
        const float4* row = (const float4*)(nodes + (long long)n * DIN);
        #pragma unroll 8
        for (int i = 0; i < DIN / 4; ++i) {
            const float4 v = row[i];
            const int j = i * 4;
            a0 += v.x * Ms[(j + 0) * 4 + 0] + v.y * Ms[(j + 1) * 4 + 0]
                + v.z * Ms[(j + 2) * 4 + 0] + v.w * Ms[(j + 3) * 4 + 0];
            a1 += v.x * Ms[(j + 0) * 4 + 1] + v.y * Ms[(j + 1) * 4 + 1]
                + v.z * Ms[(j + 2) * 4 + 1] + v.w * Ms[(j + 3) * 4 + 1];
            a2 += v.x * Ms[(j + 0) * 4 + 2] + v.y * Ms[(j + 1) * 4 + 2]
                + v.z * Ms[(j + 2) * 4 + 2] + v.w * Ms[(j + 3) * 4 + 2];
            a3 += v.x * Ms[(j + 0) * 4 + 3] + v.y * Ms[(j + 1) * 4 + 3]
                + v.z * Ms[(j + 2) * 4 + 3] + v.w * Ms[(j + 3) * 4 + 3];
        }
        AB[n] = make_float4(a0, a1, a2, a3);
    }
}

// ---------------------------------------------------------------------------
// Kernel 2: fill all P pairs.  Thread g handles pairs {2g, 2g+1}:
//   one lane-contiguous float4 store to y + 4g   (full 64-B lines/instr)
//   one lane-contiguous float2 zero  to yt + 2g
// All index math in 32-bit; row inversion via f32 sqrt on an EXACT uint32
// discriminant, with integer fixup loops absorbing the (bounded) fp error.
// ---------------------------------------------------------------------------
__global__ __launch_bounds__(256) void fill_kernel(
    const float4* __restrict__ AB,     // [8192] {A0,A1,B0,B1}
    float* __restrict__ y,             // [P][2]
    float* __restrict__ yt)            // [P]
{
    const unsigned g  = blockIdx.x * 256u + threadIdx.x;
    const unsigned p0 = 2u * g;                       // < 2^26

    // invert p0 -> (s, t):  s = floor((M - sqrt(M^2 - 8 p0)) / 2), M = 2N-1
    const unsigned M  = 2u * NN - 1u;                 // 16383
    const unsigned disc = M * M - 8u * p0;            // exact, >= 17
    const float sq = sqrtf((float)disc);              // err <= ~8/sqrt(disc) + 1ulp
    int s = (int)(((float)M - sq) * 0.5f);
    s = s < 0 ? 0 : (s > NN - 2 ? NN - 2 : s);
    unsigned rs = ((unsigned)s * (M - (unsigned)s)) >> 1;   // s*(2N-1-s)/2, <2^27
    while (p0 < rs)                           { --s; rs -= (unsigned)(NN - 1 - s); }
    while (p0 >= rs + (unsigned)(NN - 1 - s)) { rs += (unsigned)(NN - 1 - s); ++s; }
    int t = (int)(p0 - rs) + s + 1;

    float4 a  = AB[s];
    float4 b0 = AB[t];
    const float o0 = a.x + b0.z, o1 = a.y + b0.w;

    if (++t == NN) {                   // row crossing (rare)
        ++s; t = s + 1;
        a = AB[s];
    }
    float4 b1 = AB[t];
    const float o2 = a.x + b1.z, o3 = a.y + b1.w;

    *(float4*)(y + 4u * g) = make_float4(o0, o1, o2, o3);
    *(float2*)(yt + 2u * g) = make_float2(0.f, 0.f);
}

// ---------------------------------------------------------------------------
// Kernel 3: scatter edge labels.  yt[pair_idx] = 1.0 for valid (u < v) edges.
// ---------------------------------------------------------------------------
__global__ __launch_bounds__(256) void edge_kernel(
    const int* __restrict__ edges,     // [2][E]
    float* __restrict__ yt,
    int E)
{
    const int e = blockIdx.x * 256 + threadIdx.x;
    if (e >= E) return;
    const int u = edges[e];
    const int v = edges[E + e];
    if (u < v) {
        const unsigned idx = (unsigned)u * (2u * NN - u - 1u) / 2u + (unsigned)(v - u - 1);
        yt[idx] = 1.0f;
    }
}

extern "C" void kernel_launch(void* const* d_in, const int* in_sizes, int n_in,
                              void* d_out, int out_size, void* d_ws, size_t ws_size,
                              hipStream_t stream) {
    const float* nodes = (const float*)d_in[0];
    const int*   edges = (const int*)d_in[1];
    const float* W_enc = (const float*)d_in[2];
    const float* b_enc = (const float*)d_in[3];
    const float* W_cls = (const float*)d_in[4];
    const float* b_cls = (const float*)d_in[5];
    const int E = in_sizes[1] / 2;

    float4* AB = (float4*)d_ws;                   // 8192 float4 (16B aligned)

    float* y  = (float*)d_out;                    // [P][2]
    float* yt = (float*)d_out + 2 * PP;           // [P]

    ab_kernel<<<32, 256, 0, stream>>>(nodes, W_enc, b_enc, W_cls, b_cls, AB);

    // P/2 = 16,775,168 = 65528 * 256 exactly
    const int fill_blocks = (int)(PP / 512);
    fill_kernel<<<fill_blocks, 256, 0, stream>>>(AB, y, yt);

    edge_kernel<<<(E + 255) / 256, 256, 0, stream>>>(edges, yt, E);
}

// Round 5
// 94.886 us; speedup vs baseline: 1.1467x; 1.1467x over previous
//
#include <hip/hip_runtime.h>

// Problem constants (fixed by the reference file)
#define NN 8192
#define DIN 256
#define DD 256
static const long long PP = (long long)NN * (NN - 1) / 2;   // 33,550,336

typedef float __attribute__((ext_vector_type(4))) fx4;      // nontemporal-store-able
typedef float __attribute__((ext_vector_type(2))) fx2;

// ---------------------------------------------------------------------------
// Kernel 1: per-node projections, with the weight-combine fused in.
// Each block redundantly computes in LDS:
//   M[i][0..1] = sum_j W_enc[i][j] * W_cls[j][0..1]        (A projection)
//   M[i][2..3] = sum_j W_enc[i][j] * W_cls[256+j][0..1]    (B projection)
//   off[0..1]  = b_enc . W_cls[:256][:,c] + b_cls[c]
//   off[2..3]  = b_enc . W_cls[256:][:,c]
// then AB[n] = { A0, A1, B0, B1 } = nodes[n] @ M + off  for its node slice.
// ---------------------------------------------------------------------------
__global__ __launch_bounds__(256) void ab_kernel(
    const float* __restrict__ nodes,   // [8192][256]
    const float* __restrict__ W_enc,   // [256][256]
    const float* __restrict__ b_enc,   // [256]
    const float* __restrict__ W_cls,   // [512][2]
    const float* __restrict__ b_cls,   // [2]
    float4* __restrict__ AB)           // [8192] out
{
    __shared__ float wc[1024];         // W_cls staged: [512][2]
    __shared__ float Ms[1024];         // M [256][4]
    __shared__ float offs[4];
    const int tid = threadIdx.x;
    for (int i = tid; i < 1024; i += 256) wc[i] = W_cls[i];
    __syncthreads();

    // --- M row `tid` ---
    {
        float a0 = 0.f, a1 = 0.f, a2 = 0.f, a3 = 0.f;
        const float4* wrow = (const float4*)(W_enc + (long long)tid * DIN);
        #pragma unroll 8
        for (int i = 0; i < DIN / 4; ++i) {
            const float4 v = wrow[i];
            const int j = i * 4;
            a0 += v.x * wc[(j+0)*2+0] + v.y * wc[(j+1)*2+0]
                + v.z * wc[(j+2)*2+0] + v.w * wc[(j+3)*2+0];
            a1 += v.x * wc[(j+0)*2+1] + v.y * wc[(j+1)*2+1]
                + v.z * wc[(j+2)*2+1] + v.w * wc[(j+3)*2+1];
            a2 += v.x * wc[(DD+j+0)*2+0] + v.y * wc[(DD+j+1)*2+0]
                + v.z * wc[(DD+j+2)*2+0] + v.w * wc[(DD+j+3)*2+0];
            a3 += v.x * wc[(DD+j+0)*2+1] + v.y * wc[(DD+j+1)*2+1]
                + v.z * wc[(DD+j+2)*2+1] + v.w * wc[(DD+j+3)*2+1];
        }
        Ms[tid*4+0] = a0; Ms[tid*4+1] = a1; Ms[tid*4+2] = a2; Ms[tid*4+3] = a3;
    }

    // --- off (threads 0..3) ---
    if (tid < 4) {
        const int c = tid & 1;
        const int base = (tid < 2) ? 0 : DD;
        float o0 = 0.f, o1 = 0.f, o2 = 0.f, o3 = 0.f;
        for (int j = 0; j < DIN; j += 4) {
            o0 += b_enc[j+0] * wc[(base+j+0)*2+c];
            o1 += b_enc[j+1] * wc[(base+j+1)*2+c];
            o2 += b_enc[j+2] * wc[(base+j+2)*2+c];
            o3 += b_enc[j+3] * wc[(base+j+3)*2+c];
        }
        float o = (o0 + o1) + (o2 + o3);
        if (tid < 2) o += b_cls[tid];     // fold b_cls into the A half
        offs[tid] = o;
    }
    __syncthreads();

    // --- per-node projections ---
    for (int n = blockIdx.x * 256 + tid; n < NN; n += gridDim.x * 256) {
        float a0 = offs[0], a1 = offs[1], a2 = offs[2], a3 = offs[3];
        const float4* row = (const float4*)(nodes + (long long)n * DIN);
        #pragma unroll 8
        for (int i = 0; i < DIN / 4; ++i) {
            const float4 v = row[i];
            const int j = i * 4;
            a0 += v.x * Ms[(j + 0) * 4 + 0] + v.y * Ms[(j + 1) * 4 + 0]
                + v.z * Ms[(j + 2) * 4 + 0] + v.w * Ms[(j + 3) * 4 + 0];
            a1 += v.x * Ms[(j + 0) * 4 + 1] + v.y * Ms[(j + 1) * 4 + 1]
                + v.z * Ms[(j + 2) * 4 + 1] + v.w * Ms[(j + 3) * 4 + 1];
            a2 += v.x * Ms[(j + 0) * 4 + 2] + v.y * Ms[(j + 1) * 4 + 2]
                + v.z * Ms[(j + 2) * 4 + 2] + v.w * Ms[(j + 3) * 4 + 2];
            a3 += v.x * Ms[(j + 0) * 4 + 3] + v.y * Ms[(j + 1) * 4 + 3]
                + v.z * Ms[(j + 2) * 4 + 3] + v.w * Ms[(j + 3) * 4 + 3];
        }
        AB[n] = make_float4(a0, a1, a2, a3);
    }
}

// ---------------------------------------------------------------------------
// Kernel 2: fill all P pairs.  Thread g handles pairs {2g, 2g+1}:
//   one lane-contiguous NT fx4 store to y + 4g   (full 64-B lines/instr)
//   one lane-contiguous NT fx2 zero  to yt + 2g
// All index math in 32-bit; row inversion via f32 sqrt on an EXACT uint32
// discriminant (disc >= 2^24 implies sqrt(disc) >= 4096 so abs err < 1e-2;
// disc < 2^24 is exactly representable), integer fixup loops absorb the rest.
// ---------------------------------------------------------------------------
__global__ __launch_bounds__(256) void fill_kernel(
    const float4* __restrict__ AB,     // [8192] {A0,A1,B0,B1}
    float* __restrict__ y,             // [P][2]
    float* __restrict__ yt)            // [P]
{
    const unsigned g  = blockIdx.x * 256u + threadIdx.x;
    const unsigned p0 = 2u * g;                       // < 2^26

    // invert p0 -> (s, t):  s = floor((M - sqrt(M^2 - 8 p0)) / 2), M = 2N-1
    const unsigned M  = 2u * NN - 1u;                 // 16383
    const unsigned disc = M * M - 8u * p0;            // exact in uint32
    const float sq = sqrtf((float)disc);
    int s = (int)(((float)M - sq) * 0.5f);
    s = s < 0 ? 0 : (s > NN - 2 ? NN - 2 : s);
    unsigned rs = ((unsigned)s * (M - (unsigned)s)) >> 1;   // s*(2N-1-s)/2
    while (p0 < rs)                           { --s; rs -= (unsigned)(NN - 1 - s); }
    while (p0 >= rs + (unsigned)(NN - 1 - s)) { rs += (unsigned)(NN - 1 - s); ++s; }
    int t = (int)(p0 - rs) + s + 1;

    float4 a  = AB[s];
    float4 b0 = AB[t];
    const float o0 = a.x + b0.z, o1 = a.y + b0.w;

    if (++t == NN) {                   // row crossing (rare)
        ++s; t = s + 1;
        a = AB[s];
    }
    float4 b1 = AB[t];
    const float o2 = a.x + b1.z, o3 = a.y + b1.w;

    fx4 v = {o0, o1, o2, o3};
    __builtin_nontemporal_store(v, (fx4*)(y + 4u * g));
    fx2 z = {0.f, 0.f};
    __builtin_nontemporal_store(z, (fx2*)(yt + 2u * g));
}

// ---------------------------------------------------------------------------
// Kernel 3: scatter edge labels.  yt[pair_idx] = 1.0 for valid (u < v) edges.
// ---------------------------------------------------------------------------
__global__ __launch_bounds__(256) void edge_kernel(
    const int* __restrict__ edges,     // [2][E]
    float* __restrict__ yt,
    int E)
{
    const int e = blockIdx.x * 256 + threadIdx.x;
    if (e >= E) return;
    const int u = edges[e];
    const int v = edges[E + e];
    if (u < v) {
        const unsigned idx = (unsigned)u * (2u * NN - u - 1u) / 2u + (unsigned)(v - u - 1);
        yt[idx] = 1.0f;
    }
}

extern "C" void kernel_launch(void* const* d_in, const int* in_sizes, int n_in,
                              void* d_out, int out_size, void* d_ws, size_t ws_size,
                              hipStream_t stream) {
    const float* nodes = (const float*)d_in[0];
    const int*   edges = (const int*)d_in[1];
    const float* W_enc = (const float*)d_in[2];
    const float* b_enc = (const float*)d_in[3];
    const float* W_cls = (const float*)d_in[4];
    const float* b_cls = (const float*)d_in[5];
    const int E = in_sizes[1] / 2;

    float4* AB = (float4*)d_ws;                   // 8192 float4 (16B aligned)

    float* y  = (float*)d_out;                    // [P][2]
    float* yt = (float*)d_out + 2 * PP;           // [P]

    ab_kernel<<<32, 256, 0, stream>>>(nodes, W_enc, b_enc, W_cls, b_cls, AB);

    // P/2 = 16,775,168 = 65528 * 256 exactly
    const int fill_blocks = (int)(PP / 512);
    fill_kernel<<<fill_blocks, 256, 0, stream>>>(AB, y, yt);

    edge_kernel<<<(E + 255) / 256, 256, 0, stream>>>(edges, yt, E);
}

// Round 6
// 93.416 us; speedup vs baseline: 1.1647x; 1.0157x over previous
//
#include <hip/hip_runtime.h>

// Problem constants (fixed by the reference file)
#define NN 8192
#define DIN 256
#define DD 256
static const long long PP = (long long)NN * (NN - 1) / 2;   // 33,550,336 = 4096*8191

typedef float __attribute__((ext_vector_type(4))) fx4;      // nontemporal-store-able

// ---------------------------------------------------------------------------
// Kernel 1: per-node projections, with the weight-combine fused in.
// Each block redundantly computes in LDS:
//   M[i][0..1] = sum_j W_enc[i][j] * W_cls[j][0..1]        (A projection)
//   M[i][2..3] = sum_j W_enc[i][j] * W_cls[256+j][0..1]    (B projection)
//   off = b_enc @ [Wc_A | Wc_B] (+ b_cls folded into A half)
// then AB[n] = { A0, A1, B0, B1 } = nodes[n] @ M + off  for its node slice.
// ---------------------------------------------------------------------------
__global__ __launch_bounds__(256) void ab_kernel(
    const float* __restrict__ nodes,   // [8192][256]
    const float* __restrict__ W_enc,   // [256][256]
    const float* __restrict__ b_enc,   // [256]
    const float* __restrict__ W_cls,   // [512][2]
    const float* __restrict__ b_cls,   // [2]
    float4* __restrict__ AB)           // [8192] out
{
    __shared__ float wc[1024];         // W_cls staged: [512][2]
    __shared__ float Ms[1024];         // M [256][4]
    __shared__ float offs[4];
    const int tid = threadIdx.x;
    for (int i = tid; i < 1024; i += 256) wc[i] = W_cls[i];
    __syncthreads();

    // --- M row `tid` ---
    {
        float a0 = 0.f, a1 = 0.f, a2 = 0.f, a3 = 0.f;
        const float4* wrow = (const float4*)(W_enc + (long long)tid * DIN);
        #pragma unroll 8
        for (int i = 0; i < DIN / 4; ++i) {
            const float4 v = wrow[i];
            const int j = i * 4;
            a0 += v.x * wc[(j+0)*2+0] + v.y * wc[(j+1)*2+0]
                + v.z * wc[(j+2)*2+0] + v.w * wc[(j+3)*2+0];
            a1 += v.x * wc[(j+0)*2+1] + v.y * wc[(j+1)*2+1]
                + v.z * wc[(j+2)*2+1] + v.w * wc[(j+3)*2+1];
            a2 += v.x * wc[(DD+j+0)*2+0] + v.y * wc[(DD+j+1)*2+0]
                + v.z * wc[(DD+j+2)*2+0] + v.w * wc[(DD+j+3)*2+0];
            a3 += v.x * wc[(DD+j+0)*2+1] + v.y * wc[(DD+j+1)*2+1]
                + v.z * wc[(DD+j+2)*2+1] + v.w * wc[(DD+j+3)*2+1];
        }
        Ms[tid*4+0] = a0; Ms[tid*4+1] = a1; Ms[tid*4+2] = a2; Ms[tid*4+3] = a3;
    }

    // --- off (threads 0..3) ---
    if (tid < 4) {
        const int c = tid & 1;
        const int base = (tid < 2) ? 0 : DD;
        float o0 = 0.f, o1 = 0.f, o2 = 0.f, o3 = 0.f;
        for (int j = 0; j < DIN; j += 4) {
            o0 += b_enc[j+0] * wc[(base+j+0)*2+c];
            o1 += b_enc[j+1] * wc[(base+j+1)*2+c];
            o2 += b_enc[j+2] * wc[(base+j+2)*2+c];
            o3 += b_enc[j+3] * wc[(base+j+3)*2+c];
        }
        float o = (o0 + o1) + (o2 + o3);
        if (tid < 2) o += b_cls[tid];     // fold b_cls into the A half
        offs[tid] = o;
    }
    __syncthreads();

    // --- per-node projections ---
    for (int n = blockIdx.x * 256 + tid; n < NN; n += gridDim.x * 256) {
        float a0 = offs[0], a1 = offs[1], a2 = offs[2], a3 = offs[3];
        const float4* row = (const float4*)(nodes + (long long)n * DIN);
        #pragma unroll 8
        for (int i = 0; i < DIN / 4; ++i) {
            const float4 v = row[i];
            const int j = i * 4;
            a0 += v.x * Ms[(j + 0) * 4 + 0] + v.y * Ms[(j + 1) * 4 + 0]
                + v.z * Ms[(j + 2) * 4 + 0] + v.w * Ms[(j + 3) * 4 + 0];
            a1 += v.x * Ms[(j + 0) * 4 + 1] + v.y * Ms[(j + 1) * 4 + 1]
                + v.z * Ms[(j + 2) * 4 + 1] + v.w * Ms[(j + 3) * 4 + 1];
            a2 += v.x * Ms[(j + 0) * 4 + 2] + v.y * Ms[(j + 1) * 4 + 2]
                + v.z * Ms[(j + 2) * 4 + 2] + v.w * Ms[(j + 3) * 4 + 2];
            a3 += v.x * Ms[(j + 0) * 4 + 3] + v.y * Ms[(j + 1) * 4 + 3]
                + v.z * Ms[(j + 2) * 4 + 3] + v.w * Ms[(j + 3) * 4 + 3];
        }
        AB[n] = make_float4(a0, a1, a2, a3);
    }
}

// ---------------------------------------------------------------------------
// Kernel 2: fill y for all P pairs.  Thread g handles pairs {2g, 2g+1}:
// ONE lane-contiguous NT fx4 store to y + 4g.  Single pure write stream.
// Row inversion via f32 sqrt on an EXACT uint32 discriminant; integer fixup
// loops absorb bounded fp error.
// ---------------------------------------------------------------------------
__global__ __launch_bounds__(256) void fill_kernel(
    const float4* __restrict__ AB,     // [8192] {A0,A1,B0,B1}
    float* __restrict__ y)             // [P][2]
{
    const unsigned g  = blockIdx.x * 256u + threadIdx.x;
    const unsigned p0 = 2u * g;                       // < 2^26

    // invert p0 -> (s, t):  s = floor((M - sqrt(M^2 - 8 p0)) / 2), M = 2N-1
    const unsigned M  = 2u * NN - 1u;                 // 16383
    const unsigned disc = M * M - 8u * p0;            // exact in uint32
    const float sq = sqrtf((float)disc);
    int s = (int)(((float)M - sq) * 0.5f);
    s = s < 0 ? 0 : (s > NN - 2 ? NN - 2 : s);
    unsigned rs = ((unsigned)s * (M - (unsigned)s)) >> 1;   // s*(2N-1-s)/2
    while (p0 < rs)                           { --s; rs -= (unsigned)(NN - 1 - s); }
    while (p0 >= rs + (unsigned)(NN - 1 - s)) { rs += (unsigned)(NN - 1 - s); ++s; }
    int t = (int)(p0 - rs) + s + 1;

    float4 a  = AB[s];
    float4 b0 = AB[t];
    const float o0 = a.x + b0.z, o1 = a.y + b0.w;

    if (++t == NN) {                   // row crossing (rare)
        ++s; t = s + 1;
        a = AB[s];
    }
    float4 b1 = AB[t];
    const float o2 = a.x + b1.z, o3 = a.y + b1.w;

    fx4 v = {o0, o1, o2, o3};
    __builtin_nontemporal_store(v, (fx4*)(y + 4u * g));
}

// ---------------------------------------------------------------------------
// Kernel 3: zero yt.  memset-style: block covers 16 KB contiguous; each of
// 4 stores per thread is lane-contiguous (wave writes 1 KB/instr).
// P floats = 1024 fx4 * 8191 blocks exactly.
// ---------------------------------------------------------------------------
__global__ __launch_bounds__(256) void zero_kernel(float* __restrict__ yt)
{
    fx4* base = (fx4*)yt + (unsigned)blockIdx.x * 1024u + threadIdx.x;
    fx4 z = {0.f, 0.f, 0.f, 0.f};
    __builtin_nontemporal_store(z, base + 0 * 256);
    __builtin_nontemporal_store(z, base + 1 * 256);
    __builtin_nontemporal_store(z, base + 2 * 256);
    __builtin_nontemporal_store(z, base + 3 * 256);
}

// ---------------------------------------------------------------------------
// Kernel 4: scatter edge labels.  yt[pair_idx] = 1.0 for valid (u < v) edges.
// ---------------------------------------------------------------------------
__global__ __launch_bounds__(256) void edge_kernel(
    const int* __restrict__ edges,     // [2][E]
    float* __restrict__ yt,
    int E)
{
    const int e = blockIdx.x * 256 + threadIdx.x;
    if (e >= E) return;
    const int u = edges[e];
    const int v = edges[E + e];
    if (u < v) {
        const unsigned idx = (unsigned)u * (2u * NN - u - 1u) / 2u + (unsigned)(v - u - 1);
        yt[idx] = 1.0f;
    }
}

extern "C" void kernel_launch(void* const* d_in, const int* in_sizes, int n_in,
                              void* d_out, int out_size, void* d_ws, size_t ws_size,
                              hipStream_t stream) {
    const float* nodes = (const float*)d_in[0];
    const int*   edges = (const int*)d_in[1];
    const float* W_enc = (const float*)d_in[2];
    const float* b_enc = (const float*)d_in[3];
    const float* W_cls = (const float*)d_in[4];
    const float* b_cls = (const float*)d_in[5];
    const int E = in_sizes[1] / 2;

    float4* AB = (float4*)d_ws;                   // 8192 float4 (16B aligned)

    float* y  = (float*)d_out;                    // [P][2]
    float* yt = (float*)d_out + 2 * PP;           // [P]

    ab_kernel<<<32, 256, 0, stream>>>(nodes, W_enc, b_enc, W_cls, b_cls, AB);

    // P/2 = 16,775,168 = 65528 * 256 exactly
    fill_kernel<<<(int)(PP / 512), 256, 0, stream>>>(AB, y);

    // P/4 fx4 = 1024 * 8191 exactly
    zero_kernel<<<8191, 256, 0, stream>>>(yt);

    edge_kernel<<<(E + 255) / 256, 256, 0, stream>>>(edges, yt, E);
}